// Round 2
// baseline (16573.042 us; speedup 1.0000x reference)
//
#include <hip/hip_runtime.h>
#include <stdint.h>

#define T_LEN 128
#define BATCH 128
#define DHID 512
#define H 256
#define NTAGS 60
#define START_TAG 58
#define STOP_TAG 59
#define NEGV -10000.0f

typedef __attribute__((ext_vector_type(8))) short bf16x8;
typedef __attribute__((ext_vector_type(4))) short bf16x4;
typedef __attribute__((ext_vector_type(4))) float floatx4;
typedef unsigned short u16;

__device__ __forceinline__ u16 f2bf(float f) {
  union { float f; uint32_t u; } c; c.f = f;
  uint32_t u = c.u;
  u += 0x7FFFu + ((u >> 16) & 1u);
  return (u16)(u >> 16);
}
__device__ __forceinline__ float bf2f(u16 h) {
  union { uint32_t u; float f; } c; c.u = ((uint32_t)h) << 16;
  return c.f;
}
__device__ __forceinline__ float sigmf(float x) { return 1.0f / (1.0f + __expf(-x)); }
__device__ __forceinline__ float tanhfast(float x) {
  x = fminf(fmaxf(x, -15.0f), 15.0f);
  float e = __expf(2.0f * x);
  return (e - 1.0f) / (e + 1.0f);
}

// ---------------------------------------------------------------------------
// Pack fp32 weights -> bf16 workspace copies.
// ---------------------------------------------------------------------------
__global__ void pack_kernel(const float* __restrict__ whh1, const float* __restrict__ whh,
                            const float* __restrict__ wih, const float* __restrict__ fcw,
                            u16* __restrict__ whh_bf, u16* __restrict__ wih_bf,
                            u16* __restrict__ fcw_bf) {
  const int n_whh1 = 2 * 1024 * 256;
  const int n_whh  = 6 * 2 * 1024 * 256;
  const int n_wih  = 6 * 2 * 1024 * 512;
  const int n_fcw  = 64 * 512;
  const int total = n_whh1 + n_whh + n_wih + n_fcw;
  for (int i = blockIdx.x * blockDim.x + threadIdx.x; i < total; i += gridDim.x * blockDim.x) {
    if (i < n_whh1) {
      whh_bf[i] = f2bf(whh1[i]);
    } else if (i < n_whh1 + n_whh) {
      whh_bf[i] = f2bf(whh[i - n_whh1]);
    } else if (i < n_whh1 + n_whh + n_wih) {
      int j = i - n_whh1 - n_whh;
      wih_bf[j] = f2bf(wih[j]);
    } else {
      int j = i - n_whh1 - n_whh - n_wih;
      int row = j >> 9;
      fcw_bf[j] = (row < NTAGS) ? f2bf(fcw[j]) : (u16)0;
    }
  }
}

// ---------------------------------------------------------------------------
// Layer-1 xw, TRANSPOSED layout: xw[t][col(2048)][b(128)].
// idx = (t*2048 + col)*128 + b. Writes coalesced.
// ---------------------------------------------------------------------------
__global__ void xw1_kernel(const float* __restrict__ sent, const float* __restrict__ wih1,
                           const float* __restrict__ b1, u16* __restrict__ xw) {
  int idx = blockIdx.x * blockDim.x + threadIdx.x;
  int b = idx & 127;
  int rest = idx >> 7;
  int col = rest & 2047;
  int t = rest >> 11;
  int row = t * BATCH + b;
  const float* x = sent + row * 3;
  const float* w = wih1 + col * 3;
  float a = b1[col] + x[0] * w[0] + x[1] * w[1] + x[2] * w[2];
  xw[idx] = f2bf(a);
}

// ---------------------------------------------------------------------------
// xw GEMM layers 2..7: A=relu(cur)[+relu(prev)] [16384x512], W [2048][512] bf16.
// Out transposed: xw[t][col][b]. Block: 64 M x 256 N; wave = 64-col slice x 64 rows
// (acc 4x4) so B-frags are loaded once per block (no intra-block redundancy).
// ---------------------------------------------------------------------------
__launch_bounds__(256, 4)
__global__ void gemm_xw_kernel(const u16* __restrict__ cur, const u16* __restrict__ prev,
                               const u16* __restrict__ W, const float* __restrict__ bias,
                               u16* __restrict__ xw) {
  __shared__ __align__(16) u16 As[64][72];
  const int nbase = blockIdx.x * 256;
  const int m0 = blockIdx.y * 64;
  const int tid = threadIdx.x;
  const int wv = tid >> 6, ln = tid & 63;
  const int c16 = ln & 15, q = ln >> 4;
  const int ncol0 = nbase + wv * 64;  // this wave's 64-col slice

  floatx4 acc[4][4];  // [nt][mt]
#pragma unroll
  for (int i = 0; i < 4; ++i)
#pragma unroll
    for (int j = 0; j < 4; ++j) { acc[i][j][0] = 0.f; acc[i][j][1] = 0.f; acc[i][j][2] = 0.f; acc[i][j][3] = 0.f; }

  for (int kc = 0; kc < 8; ++kc) {
    // stage A[64][64] (relu + optional residual)
    {
      int u = tid * 2;
#pragma unroll
      for (int z = 0; z < 2; ++z, ++u) {
        int r = u >> 3, cu = (u & 7) * 8;
        int gaddr = (m0 + r) * DHID + kc * 64 + cu;
        bf16x8 a8 = *(const bf16x8*)(cur + gaddr);
        u16* ap = (u16*)&a8;
        if (prev) {
          bf16x8 p8 = *(const bf16x8*)(prev + gaddr);
          u16* pp = (u16*)&p8;
#pragma unroll
          for (int e = 0; e < 8; ++e) {
            float va = (ap[e] & 0x8000) ? 0.f : bf2f(ap[e]);
            float vp = (pp[e] & 0x8000) ? 0.f : bf2f(pp[e]);
            ap[e] = f2bf(va + vp);
          }
        } else {
#pragma unroll
          for (int e = 0; e < 8; ++e) if (ap[e] & 0x8000) ap[e] = 0;
        }
        *(bf16x8*)(&As[r][cu]) = a8;
      }
    }
    __syncthreads();
#pragma unroll
    for (int kt = 0; kt < 2; ++kt) {
      int kg = kc * 64 + kt * 32 + q * 8;
      bf16x8 bfr[4];
#pragma unroll
      for (int nt = 0; nt < 4; ++nt)
        bfr[nt] = *(const bf16x8*)(W + (ncol0 + nt * 16 + c16) * DHID + kg);
      bf16x8 afr[4];
#pragma unroll
      for (int mt = 0; mt < 4; ++mt)
        afr[mt] = *(const bf16x8*)(&As[mt * 16 + c16][kt * 32 + q * 8]);
#pragma unroll
      for (int nt = 0; nt < 4; ++nt)
#pragma unroll
        for (int mt = 0; mt < 4; ++mt)
          acc[nt][mt] = __builtin_amdgcn_mfma_f32_16x16x32_bf16(afr[mt], bfr[nt], acc[nt][mt], 0, 0, 0);
    }
    __syncthreads();
  }
  // epilogue: transposed store, 4 rows (=batch) packed per 8-B store
  const int t = m0 >> 7;
  const int bb = (m0 & 127) + q * 4;  // +mt*16
#pragma unroll
  for (int nt = 0; nt < 4; ++nt) {
    int col = ncol0 + nt * 16 + c16;
    float bv = bias[col];
#pragma unroll
    for (int mt = 0; mt < 4; ++mt) {
      bf16x4 v;
#pragma unroll
      for (int r = 0; r < 4; ++r) v[r] = (short)f2bf(acc[nt][mt][r] + bv);
      *(bf16x4*)(xw + ((size_t)t * 2048 + col) * 128 + bb + mt * 16) = v;
    }
  }
}

// ---------------------------------------------------------------------------
// Persistent LSTM scan. Grid (4 batch-chunks x 2 dirs), block 512 (8 waves).
// Wave owns 32 h-cols (all 4 gates). h double-buffered in LDS, c in regs.
// Per step: coalesced xw loads (transposed layout) issued early; W_hh B-frags
// double-buffered (group g+1 loads overlap group g MFMAs); gates processed
// per st-half to cap acc live range.
// ---------------------------------------------------------------------------
__launch_bounds__(512, 2)
__global__ void scan_kernel(const u16* __restrict__ whh, const u16* __restrict__ xw,
                            const float* __restrict__ h0, const float* __restrict__ c0,
                            u16* __restrict__ obuf) {
  __shared__ __align__(16) u16 hbuf[2][32][264];
  const int b0 = blockIdx.x * 32;
  const int dir = blockIdx.y;
  const int tid = threadIdx.x;
  const int wv = tid >> 6, ln = tid & 63;
  const int c16 = ln & 15, q = ln >> 4;

  // init h into hbuf[0]
#pragma unroll
  for (int e = 0; e < 16; ++e) {
    int idx = e * 512 + tid;
    int r = idx >> 8, cc = idx & 255;
    hbuf[0][r][cc] = f2bf(h0[(dir * BATCH + b0 + r) * H + cc]);
  }
  float creg[2][2][4];  // [mt][st][r]
#pragma unroll
  for (int mt = 0; mt < 2; ++mt)
#pragma unroll
    for (int st = 0; st < 2; ++st)
#pragma unroll
      for (int r = 0; r < 4; ++r) {
        int b = b0 + mt * 16 + q * 4 + r;
        int j = wv * 32 + st * 16 + c16;
        creg[mt][st][r] = c0[(dir * BATCH + b) * H + j];
      }
  __syncthreads();

  // per-lane 32-bit offsets (elements) for the 16 xw loads: [g][st][mt]
  int xoff[16];
#pragma unroll
  for (int g = 0; g < 4; ++g)
#pragma unroll
    for (int st = 0; st < 2; ++st)
#pragma unroll
      for (int mt = 0; mt < 2; ++mt)
        xoff[(g * 2 + st) * 2 + mt] =
            (g * 256 + (wv * 2 + st) * 16 + c16) * 128 + b0 + mt * 16 + q * 4;

  // W row offsets per (g,st) group (constant across steps)
  int woff[8];
#pragma unroll
  for (int g = 0; g < 4; ++g)
#pragma unroll
    for (int st = 0; st < 2; ++st)
      woff[g * 2 + st] = (g * H + (wv * 2 + st) * 16 + c16) * H + q * 8;

  const u16* wbase = whh + dir * 1024 * H;
  const int t0 = dir ? (T_LEN - 1) : 0;
  const u16* xwt = xw + (size_t)t0 * 2048 * 128 + (size_t)dir * 1024 * 128;
  const ptrdiff_t xstep = (dir ? -1 : 1) * (ptrdiff_t)(2048 * 128);
  u16* obt = obuf + (size_t)t0 * BATCH * DHID;
  const ptrdiff_t ostep = (dir ? -1 : 1) * (ptrdiff_t)(BATCH * DHID);
  const int ocol = dir * H + wv * 32 + c16;  // + st*16

  for (int s = 0; s < T_LEN; ++s) {
    const int cb = s & 1, nb = cb ^ 1;

    // 1) issue this step's xw loads (coalesced 8-B each; consumed at acc-init)
    bf16x4 xwv[16];
#pragma unroll
    for (int i = 0; i < 16; ++i) xwv[i] = *(const bf16x4*)(xwt + xoff[i]);

    // 2) A-frags from LDS h
    bf16x8 afrag[2][8];
#pragma unroll
    for (int mt = 0; mt < 2; ++mt)
#pragma unroll
      for (int kt = 0; kt < 8; ++kt)
        afrag[mt][kt] = *(const bf16x8*)(&hbuf[cb][mt * 16 + c16][kt * 32 + q * 8]);

    // 3) per st-half: pipelined W loads + MFMA, then gates
#pragma unroll
    for (int st = 0; st < 2; ++st) {
      floatx4 acc[4][2];  // [g][mt]
#pragma unroll
      for (int g = 0; g < 4; ++g)
#pragma unroll
        for (int mt = 0; mt < 2; ++mt)
#pragma unroll
          for (int r = 0; r < 4; ++r)
            acc[g][mt][r] = bf2f((u16)xwv[(g * 2 + st) * 2 + mt][r]);

      bf16x8 bw[2][8];
      {
        const u16* wr = wbase + woff[0 * 2 + st];
#pragma unroll
        for (int kt = 0; kt < 8; ++kt) bw[0][kt] = *(const bf16x8*)(wr + kt * 32);
      }
#pragma unroll
      for (int g = 0; g < 4; ++g) {
        if (g < 3) {
          const u16* wr = wbase + woff[(g + 1) * 2 + st];
#pragma unroll
          for (int kt = 0; kt < 8; ++kt) bw[(g + 1) & 1][kt] = *(const bf16x8*)(wr + kt * 32);
        }
#pragma unroll
        for (int kt = 0; kt < 8; ++kt)
#pragma unroll
          for (int mt = 0; mt < 2; ++mt)
            acc[g][mt] = __builtin_amdgcn_mfma_f32_16x16x32_bf16(afrag[mt][kt], bw[g & 1][kt],
                                                                 acc[g][mt], 0, 0, 0);
      }
      // gates for this st-half
#pragma unroll
      for (int mt = 0; mt < 2; ++mt)
#pragma unroll
        for (int r = 0; r < 4; ++r) {
          float ig = sigmf(acc[0][mt][r]);
          float fg = sigmf(acc[1][mt][r]);
          float gg = tanhfast(acc[2][mt][r]);
          float og = sigmf(acc[3][mt][r]);
          float cn = fg * creg[mt][st][r] + ig * gg;
          creg[mt][st][r] = cn;
          float hv = og * tanhfast(cn);
          u16 hb = f2bf(hv);
          int rloc = mt * 16 + q * 4 + r;
          hbuf[nb][rloc][wv * 32 + st * 16 + c16] = hb;
          obt[(size_t)(b0 + rloc) * DHID + ocol + st * 16] = hb;
        }
    }
    xwt += xstep;
    obt += ostep;
    __syncthreads();
  }
}

// ---------------------------------------------------------------------------
// FC: feats[16384][64] = out7[16384][512] @ fcw^T + fc_b
// ---------------------------------------------------------------------------
__launch_bounds__(256, 4)
__global__ void fc_kernel(const u16* __restrict__ A, const u16* __restrict__ W,
                          const float* __restrict__ fb, float* __restrict__ feats) {
  const int tid = threadIdx.x, wv = tid >> 6, ln = tid & 63;
  const int c16 = ln & 15, q = ln >> 4;
  const int m0 = blockIdx.x * 64 + wv * 16;
  floatx4 acc[4];
#pragma unroll
  for (int i = 0; i < 4; ++i) { acc[i][0] = 0.f; acc[i][1] = 0.f; acc[i][2] = 0.f; acc[i][3] = 0.f; }
#pragma unroll
  for (int kt = 0; kt < 16; ++kt) {
    bf16x8 a = *(const bf16x8*)(A + (m0 + c16) * DHID + kt * 32 + q * 8);
#pragma unroll
    for (int nt = 0; nt < 4; ++nt) {
      bf16x8 b = *(const bf16x8*)(W + (nt * 16 + c16) * DHID + kt * 32 + q * 8);
      acc[nt] = __builtin_amdgcn_mfma_f32_16x16x32_bf16(a, b, acc[nt], 0, 0, 0);
    }
  }
#pragma unroll
  for (int nt = 0; nt < 4; ++nt) {
    int n = nt * 16 + c16;
    if (n < NTAGS) {
      float bv = fb[n];
#pragma unroll
      for (int r = 0; r < 4; ++r)
        feats[(m0 + q * 4 + r) * 64 + n] = acc[nt][r] + bv;
    }
  }
}

// ---------------------------------------------------------------------------
// CRF: one wave per batch item.
// ---------------------------------------------------------------------------
__launch_bounds__(64, 1)
__global__ void crf_kernel(const float* __restrict__ feats, const float* __restrict__ trans,
                           const int* __restrict__ tags, float* __restrict__ out) {
  __shared__ float Tl[60][65];
  __shared__ float abuf[2][64];
  const int b = blockIdx.x;
  const int ln = threadIdx.x;
  for (int i = ln; i < 3600; i += 64) Tl[i / 60][i % 60] = trans[i];
  __syncthreads();

  float gsc = 0.f;
  for (int t = ln; t < T_LEN; t += 64) {
    int tg = tags[t * BATCH + b];
    int pv = (t == 0) ? START_TAG : tags[(t - 1) * BATCH + b];
    gsc += Tl[tg][pv] + feats[(t * BATCH + b) * 64 + tg];
  }
#pragma unroll
  for (int off = 32; off > 0; off >>= 1) gsc += __shfl_down(gsc, off);
  if (ln == 0) gsc += Tl[STOP_TAG][tags[(T_LEN - 1) * BATCH + b]];

  abuf[0][ln] = (ln == START_TAG) ? 0.f : NEGV;
  __syncthreads();
  const float* Trow = Tl[ln < NTAGS ? ln : 0];
  const int myk = (ln < NTAGS) ? ln : 0;
  for (int t = 0; t < T_LEN; ++t) {
    const int cb = t & 1, nb2 = cb ^ 1;
    float m = -1e30f;
    for (int p = 0; p < NTAGS; ++p) m = fmaxf(m, abuf[cb][p] + Trow[p]);
    float ssum = 0.f;
    for (int p = 0; p < NTAGS; ++p) ssum += __expf(abuf[cb][p] + Trow[p] - m);
    float nv = m + __logf(ssum) + feats[(t * BATCH + b) * 64 + myk];
    abuf[nb2][ln] = (ln < NTAGS) ? nv : NEGV;
    __syncthreads();
  }

  float v = (ln < NTAGS) ? (abuf[T_LEN & 1][ln] + Tl[STOP_TAG][ln]) : -1e30f;
  float mm = v;
#pragma unroll
  for (int off = 32; off > 0; off >>= 1) mm = fmaxf(mm, __shfl_down(mm, off));
  mm = __shfl(mm, 0);
  float es = __expf(v - mm);
#pragma unroll
  for (int off = 32; off > 0; off >>= 1) es += __shfl_down(es, off);
  if (ln == 0) out[b] = mm + __logf(es) - gsc;
}

// ---------------------------------------------------------------------------
extern "C" void kernel_launch(void* const* d_in, const int* in_sizes, int n_in,
                              void* d_out, int out_size, void* d_ws, size_t ws_size,
                              hipStream_t stream) {
  (void)in_sizes; (void)n_in; (void)out_size; (void)ws_size;
  const float* sent  = (const float*)d_in[0];
  const int*   tags  = (const int*)d_in[1];
  const float* wih1  = (const float*)d_in[2];
  const float* whh1  = (const float*)d_in[3];
  const float* b1    = (const float*)d_in[4];
  const float* wih   = (const float*)d_in[5];
  const float* whh   = (const float*)d_in[6];
  const float* bias  = (const float*)d_in[7];
  const float* fcw   = (const float*)d_in[8];
  const float* fcb   = (const float*)d_in[9];
  const float* h0    = (const float*)d_in[10];
  const float* c0    = (const float*)d_in[11];
  const float* trans = (const float*)d_in[12];
  float* out = (float*)d_out;

  char* ws = (char*)d_ws;
  size_t off = 0;
  auto alloc = [&](size_t bytes) -> void* {
    void* p = ws + off;
    off = (off + bytes + 255) & ~(size_t)255;
    return p;
  };
  u16* whh_bf = (u16*)alloc((size_t)7 * 2 * 1024 * 256 * 2);
  u16* wih_bf = (u16*)alloc((size_t)6 * 2 * 1024 * 512 * 2);
  u16* fcw_bf = (u16*)alloc((size_t)64 * 512 * 2);
  u16* xw     = (u16*)alloc((size_t)16384 * 2048 * 2);
  u16* ob[3];
  for (int i = 0; i < 3; ++i) ob[i] = (u16*)alloc((size_t)16384 * 512 * 2);
  float* feats = (float*)alloc((size_t)16384 * 64 * 4);

  hipLaunchKernelGGL(pack_kernel, dim3(4096), dim3(256), 0, stream,
                     whh1, whh, wih, fcw, whh_bf, wih_bf, fcw_bf);
  hipLaunchKernelGGL(xw1_kernel, dim3(131072), dim3(256), 0, stream, sent, wih1, b1, xw);
  hipLaunchKernelGGL(scan_kernel, dim3(4, 2), dim3(512), 0, stream,
                     whh_bf, xw, h0, c0, ob[0]);
  for (int L = 1; L < 7; ++L) {
    const u16* curb = ob[(L - 1) % 3];
    const u16* prevb = (L >= 2) ? ob[(L - 2) % 3] : nullptr;
    hipLaunchKernelGGL(gemm_xw_kernel, dim3(8, 256), dim3(256), 0, stream,
                       curb, prevb, wih_bf + (size_t)(L - 1) * 2 * 1024 * 512,
                       bias + (size_t)(L - 1) * 2048, xw);
    hipLaunchKernelGGL(scan_kernel, dim3(4, 2), dim3(512), 0, stream,
                       whh_bf + (size_t)L * 2 * 1024 * 256, xw,
                       h0 + (size_t)L * 2 * 128 * 256, c0 + (size_t)L * 2 * 128 * 256,
                       ob[L % 3]);
  }
  hipLaunchKernelGGL(fc_kernel, dim3(256), dim3(256), 0, stream, ob[0], fcw_bf, fcb, feats);
  hipLaunchKernelGGL(crf_kernel, dim3(128), dim3(64), 0, stream, feats, trans, tags, out);
}

// Round 3
// 6683.439 us; speedup vs baseline: 2.4797x; 2.4797x over previous
//
#include <hip/hip_runtime.h>
#include <stdint.h>

#define T_LEN 128
#define BATCH 128
#define DHID 512
#define H 256
#define NTAGS 60
#define START_TAG 58
#define STOP_TAG 59
#define NEGV -10000.0f

typedef __attribute__((ext_vector_type(8))) short bf16x8;
typedef __attribute__((ext_vector_type(4))) short bf16x4;
typedef __attribute__((ext_vector_type(4))) float floatx4;
typedef unsigned short u16;
typedef unsigned long long u64c;

__device__ __forceinline__ u16 f2bf(float f) {
  union { float f; uint32_t u; } c; c.f = f;
  uint32_t u = c.u;
  u += 0x7FFFu + ((u >> 16) & 1u);
  return (u16)(u >> 16);
}
__device__ __forceinline__ float bf2f(u16 h) {
  union { uint32_t u; float f; } c; c.u = ((uint32_t)h) << 16;
  return c.f;
}
__device__ __forceinline__ float sigmf(float x) { return 1.0f / (1.0f + __expf(-x)); }
__device__ __forceinline__ float tanhfast(float x) {
  x = fminf(fmaxf(x, -15.0f), 15.0f);
  float e = __expf(2.0f * x);
  return (e - 1.0f) / (e + 1.0f);
}

// ---------------------------------------------------------------------------
// Pack fp32 weights -> bf16 workspace copies.
// ---------------------------------------------------------------------------
__global__ void pack_kernel(const float* __restrict__ whh1, const float* __restrict__ whh,
                            const float* __restrict__ wih, const float* __restrict__ fcw,
                            u16* __restrict__ whh_bf, u16* __restrict__ wih_bf,
                            u16* __restrict__ fcw_bf) {
  const int n_whh1 = 2 * 1024 * 256;
  const int n_whh  = 6 * 2 * 1024 * 256;
  const int n_wih  = 6 * 2 * 1024 * 512;
  const int n_fcw  = 64 * 512;
  const int total = n_whh1 + n_whh + n_wih + n_fcw;
  for (int i = blockIdx.x * blockDim.x + threadIdx.x; i < total; i += gridDim.x * blockDim.x) {
    if (i < n_whh1) {
      whh_bf[i] = f2bf(whh1[i]);
    } else if (i < n_whh1 + n_whh) {
      whh_bf[i] = f2bf(whh[i - n_whh1]);
    } else if (i < n_whh1 + n_whh + n_wih) {
      int j = i - n_whh1 - n_whh;
      wih_bf[j] = f2bf(wih[j]);
    } else {
      int j = i - n_whh1 - n_whh - n_wih;
      int row = j >> 9;
      fcw_bf[j] = (row < NTAGS) ? f2bf(fcw[j]) : (u16)0;
    }
  }
}

// ---------------------------------------------------------------------------
// Layer-1 xw, TRANSPOSED layout: xw[t][col(2048)][b(128)].
// ---------------------------------------------------------------------------
__global__ void xw1_kernel(const float* __restrict__ sent, const float* __restrict__ wih1,
                           const float* __restrict__ b1, u16* __restrict__ xw) {
  int idx = blockIdx.x * blockDim.x + threadIdx.x;
  int b = idx & 127;
  int rest = idx >> 7;
  int col = rest & 2047;
  int t = rest >> 11;
  int row = t * BATCH + b;
  const float* x = sent + row * 3;
  const float* w = wih1 + col * 3;
  float a = b1[col] + x[0] * w[0] + x[1] * w[1] + x[2] * w[2];
  xw[idx] = f2bf(a);
}

// ---------------------------------------------------------------------------
// xw GEMM layers 2..7 (unchanged from R2): out transposed xw[t][col][b].
// ---------------------------------------------------------------------------
__launch_bounds__(256, 4)
__global__ void gemm_xw_kernel(const u16* __restrict__ cur, const u16* __restrict__ prev,
                               const u16* __restrict__ W, const float* __restrict__ bias,
                               u16* __restrict__ xw) {
  __shared__ __align__(16) u16 As[64][72];
  const int nbase = blockIdx.x * 256;
  const int m0 = blockIdx.y * 64;
  const int tid = threadIdx.x;
  const int wv = tid >> 6, ln = tid & 63;
  const int c16 = ln & 15, q = ln >> 4;
  const int ncol0 = nbase + wv * 64;

  floatx4 acc[4][4];
#pragma unroll
  for (int i = 0; i < 4; ++i)
#pragma unroll
    for (int j = 0; j < 4; ++j) { acc[i][j][0] = 0.f; acc[i][j][1] = 0.f; acc[i][j][2] = 0.f; acc[i][j][3] = 0.f; }

  for (int kc = 0; kc < 8; ++kc) {
    {
      int u = tid * 2;
#pragma unroll
      for (int z = 0; z < 2; ++z, ++u) {
        int r = u >> 3, cu = (u & 7) * 8;
        int gaddr = (m0 + r) * DHID + kc * 64 + cu;
        bf16x8 a8 = *(const bf16x8*)(cur + gaddr);
        u16* ap = (u16*)&a8;
        if (prev) {
          bf16x8 p8 = *(const bf16x8*)(prev + gaddr);
          u16* pp = (u16*)&p8;
#pragma unroll
          for (int e = 0; e < 8; ++e) {
            float va = (ap[e] & 0x8000) ? 0.f : bf2f(ap[e]);
            float vp = (pp[e] & 0x8000) ? 0.f : bf2f(pp[e]);
            ap[e] = f2bf(va + vp);
          }
        } else {
#pragma unroll
          for (int e = 0; e < 8; ++e) if (ap[e] & 0x8000) ap[e] = 0;
        }
        *(bf16x8*)(&As[r][cu]) = a8;
      }
    }
    __syncthreads();
#pragma unroll
    for (int kt = 0; kt < 2; ++kt) {
      int kg = kc * 64 + kt * 32 + q * 8;
      bf16x8 bfr[4];
#pragma unroll
      for (int nt = 0; nt < 4; ++nt)
        bfr[nt] = *(const bf16x8*)(W + (ncol0 + nt * 16 + c16) * DHID + kg);
      bf16x8 afr[4];
#pragma unroll
      for (int mt = 0; mt < 4; ++mt)
        afr[mt] = *(const bf16x8*)(&As[mt * 16 + c16][kt * 32 + q * 8]);
#pragma unroll
      for (int nt = 0; nt < 4; ++nt)
#pragma unroll
        for (int mt = 0; mt < 4; ++mt)
          acc[nt][mt] = __builtin_amdgcn_mfma_f32_16x16x32_bf16(afr[mt], bfr[nt], acc[nt][mt], 0, 0, 0);
    }
    __syncthreads();
  }
  const int t = m0 >> 7;
  const int bb = (m0 & 127) + q * 4;
#pragma unroll
  for (int nt = 0; nt < 4; ++nt) {
    int col = ncol0 + nt * 16 + c16;
    float bv = bias[col];
#pragma unroll
    for (int mt = 0; mt < 4; ++mt) {
      bf16x4 v;
#pragma unroll
      for (int r = 0; r < 4; ++r) v[r] = (short)f2bf(acc[nt][mt][r] + bv);
      *(bf16x4*)(xw + ((size_t)t * 2048 + col) * 128 + bb + mt * 16) = v;
    }
  }
}

// ---------------------------------------------------------------------------
// LSTM scan, hidden-split design. Grid: 32 blocks of 256 threads (4 waves).
//   blockIdx.x = dir*16 + bc*4 + dq
//   dir: direction; bc: batch-chunk of 32; dq: 64-h-col quarter.
// Block keeps its W_hh slice (4 gates x 64 cols x 256 = 128 KB) in LDS.
// Per step, group (dir,bc) of 4 blocks exchanges h (bf16) through LLC via
// agent-scope stores/loads; sync via relaxed agent atomic counter per group
// (barrier's vmcnt(0) drain orders data before the flag bump).
// hG layout: [parity][dir*128+b][256 cols] bf16.
// ---------------------------------------------------------------------------
__launch_bounds__(256, 1)
__global__ void scan_kernel(const u16* __restrict__ whh, const u16* __restrict__ xw,
                            const float* __restrict__ h0, const float* __restrict__ c0,
                            u16* __restrict__ obuf, u16* __restrict__ hG,
                            unsigned* __restrict__ cnt) {
  __shared__ __align__(16) u16 Wl[256][264];   // 132 KB
  __shared__ __align__(16) u16 hstage[32][72]; // 4.5 KB
  const int dq  = blockIdx.x & 3;
  const int bc  = (blockIdx.x >> 2) & 3;
  const int dir = blockIdx.x >> 4;
  const int b0  = bc * 32;
  const int tid = threadIdx.x;
  const int wv = tid >> 6, ln = tid & 63;
  const int c16 = ln & 15, q = ln >> 4;
  const int colb = dq * 64 + wv * 16;          // this wave's 16 h-cols
  unsigned* grpcnt = cnt + (dir * 4 + bc) * 32;

  // --- one-time: W slice -> LDS ---
  {
    int g = tid >> 6, lc = tid & 63;
    const u16* wrow = whh + ((size_t)dir * 1024 + g * 256 + dq * 64 + lc) * H;
#pragma unroll
    for (int kk = 0; kk < 256; kk += 8)
      *(bf16x8*)(&Wl[g * 64 + lc][kk]) = *(const bf16x8*)(wrow + kk);
  }
  // --- one-time: publish h0 slice into hG[0] (agent stores) ---
  {
    int bl = tid >> 3, cr = (tid & 7) * 8;
    const float* hrow = h0 + ((size_t)dir * BATCH + b0 + bl) * H + dq * 64 + cr;
    u16 tmp[8];
#pragma unroll
    for (int j = 0; j < 8; ++j) tmp[j] = f2bf(hrow[j]);
    u64c* src = (u64c*)tmp;
    u64c* dst = (u64c*)(hG + ((size_t)dir * BATCH + b0 + bl) * H + dq * 64 + cr);
    __hip_atomic_store(&dst[0], src[0], __ATOMIC_RELAXED, __HIP_MEMORY_SCOPE_AGENT);
    __hip_atomic_store(&dst[1], src[1], __ATOMIC_RELAXED, __HIP_MEMORY_SCOPE_AGENT);
  }
  // --- c init (fp32, registers) ---
  float creg[2][4];  // [mt][r]
#pragma unroll
  for (int mt = 0; mt < 2; ++mt)
#pragma unroll
    for (int r = 0; r < 4; ++r)
      creg[mt][r] = c0[((size_t)dir * BATCH + b0 + mt * 16 + q * 4 + r) * H + colb + c16];

  __syncthreads();  // drains vmcnt: h0 publish complete at LLC; W LDS visible
  if (tid == 0) __hip_atomic_fetch_add(grpcnt, 1u, __ATOMIC_RELAXED, __HIP_MEMORY_SCOPE_AGENT);

  const size_t hGhalf = (size_t)2 * BATCH * H;  // elements per parity buffer

  for (int s = 0; s < T_LEN; ++s) {
    const int t = dir ? (T_LEN - 1 - s) : s;
    const int p = s & 1, pn = p ^ 1;

    // 1) xw loads (independent of peers) — [t][col][b] layout, 8-B coalesced
    bf16x4 xwv[4][2];
#pragma unroll
    for (int g = 0; g < 4; ++g)
#pragma unroll
      for (int mt = 0; mt < 2; ++mt)
        xwv[g][mt] = *(const bf16x4*)(xw + ((size_t)t * 2048 + dir * 1024 + g * 256 + colb + c16) * 128 +
                                      b0 + mt * 16 + q * 4);

    // 2) wait for step-s input h to be fully published
    const unsigned target = 4u * (unsigned)(s + 1);
    while (__hip_atomic_load(grpcnt, __ATOMIC_RELAXED, __HIP_MEMORY_SCOPE_AGENT) < target)
      __builtin_amdgcn_s_sleep(1);

    // 3) A-fragments from hG[p] via agent (LLC) loads
    bf16x8 afrag[2][8];
#pragma unroll
    for (int mt = 0; mt < 2; ++mt)
#pragma unroll
      for (int kt = 0; kt < 8; ++kt) {
        const u64c* srcp = (const u64c*)(hG + p * hGhalf +
                                         ((size_t)dir * BATCH + b0 + mt * 16 + c16) * H + kt * 32 + q * 8);
        union { u64c v[2]; bf16x8 f; } u;
        u.v[0] = __hip_atomic_load(&srcp[0], __ATOMIC_RELAXED, __HIP_MEMORY_SCOPE_AGENT);
        u.v[1] = __hip_atomic_load(&srcp[1], __ATOMIC_RELAXED, __HIP_MEMORY_SCOPE_AGENT);
        afrag[mt][kt] = u.f;
      }

    // 4) MFMA: acc init from xw, B-frags from LDS W
    floatx4 acc[4][2];
#pragma unroll
    for (int g = 0; g < 4; ++g)
#pragma unroll
      for (int mt = 0; mt < 2; ++mt)
#pragma unroll
        for (int r = 0; r < 4; ++r)
          acc[g][mt][r] = bf2f((u16)xwv[g][mt][r]);
#pragma unroll
    for (int g = 0; g < 4; ++g) {
      bf16x8 bfr[8];
#pragma unroll
      for (int kt = 0; kt < 8; ++kt)
        bfr[kt] = *(const bf16x8*)(&Wl[g * 64 + wv * 16 + c16][kt * 32 + q * 8]);
#pragma unroll
      for (int kt = 0; kt < 8; ++kt)
#pragma unroll
        for (int mt = 0; mt < 2; ++mt)
          acc[g][mt] = __builtin_amdgcn_mfma_f32_16x16x32_bf16(afrag[mt][kt], bfr[kt], acc[g][mt], 0, 0, 0);
    }

    // 5) gates -> h' into hstage (LDS)
#pragma unroll
    for (int mt = 0; mt < 2; ++mt)
#pragma unroll
      for (int r = 0; r < 4; ++r) {
        float ig = sigmf(acc[0][mt][r]);
        float fg = sigmf(acc[1][mt][r]);
        float gg = tanhfast(acc[2][mt][r]);
        float og = sigmf(acc[3][mt][r]);
        float cn = fg * creg[mt][r] + ig * gg;
        creg[mt][r] = cn;
        hstage[mt * 16 + q * 4 + r][wv * 16 + c16] = f2bf(og * tanhfast(cn));
      }
    __syncthreads();

    // 6) publish h' (agent stores to hG[pn]) + obuf write (normal, 16-B)
    {
      int bl = tid >> 3, cr = (tid & 7) * 8;
      bf16x8 hv = *(const bf16x8*)(&hstage[bl][cr]);
      u64c* src = (u64c*)&hv;
      u64c* dst = (u64c*)(hG + pn * hGhalf + ((size_t)dir * BATCH + b0 + bl) * H + dq * 64 + cr);
      __hip_atomic_store(&dst[0], src[0], __ATOMIC_RELAXED, __HIP_MEMORY_SCOPE_AGENT);
      __hip_atomic_store(&dst[1], src[1], __ATOMIC_RELAXED, __HIP_MEMORY_SCOPE_AGENT);
      *(bf16x8*)(obuf + ((size_t)t * BATCH + b0 + bl) * DHID + dir * H + dq * 64 + cr) = hv;
    }
    __syncthreads();  // drains vmcnt in every wave -> all publishes at LLC; also hstage WAR
    if (tid == 0) __hip_atomic_fetch_add(grpcnt, 1u, __ATOMIC_RELAXED, __HIP_MEMORY_SCOPE_AGENT);
  }
}

// ---------------------------------------------------------------------------
// FC: feats[16384][64] = out7[16384][512] @ fcw^T + fc_b
// ---------------------------------------------------------------------------
__launch_bounds__(256, 4)
__global__ void fc_kernel(const u16* __restrict__ A, const u16* __restrict__ W,
                          const float* __restrict__ fb, float* __restrict__ feats) {
  const int tid = threadIdx.x, wv = tid >> 6, ln = tid & 63;
  const int c16 = ln & 15, q = ln >> 4;
  const int m0 = blockIdx.x * 64 + wv * 16;
  floatx4 acc[4];
#pragma unroll
  for (int i = 0; i < 4; ++i) { acc[i][0] = 0.f; acc[i][1] = 0.f; acc[i][2] = 0.f; acc[i][3] = 0.f; }
#pragma unroll
  for (int kt = 0; kt < 16; ++kt) {
    bf16x8 a = *(const bf16x8*)(A + (m0 + c16) * DHID + kt * 32 + q * 8);
#pragma unroll
    for (int nt = 0; nt < 4; ++nt) {
      bf16x8 b = *(const bf16x8*)(W + (nt * 16 + c16) * DHID + kt * 32 + q * 8);
      acc[nt] = __builtin_amdgcn_mfma_f32_16x16x32_bf16(a, b, acc[nt], 0, 0, 0);
    }
  }
#pragma unroll
  for (int nt = 0; nt < 4; ++nt) {
    int n = nt * 16 + c16;
    if (n < NTAGS) {
      float bv = fb[n];
#pragma unroll
      for (int r = 0; r < 4; ++r)
        feats[(m0 + q * 4 + r) * 64 + n] = acc[nt][r] + bv;
    }
  }
}

// ---------------------------------------------------------------------------
// CRF: one wave per batch item.
// ---------------------------------------------------------------------------
__launch_bounds__(64, 1)
__global__ void crf_kernel(const float* __restrict__ feats, const float* __restrict__ trans,
                           const int* __restrict__ tags, float* __restrict__ out) {
  __shared__ float Tl[60][65];
  __shared__ float abuf[2][64];
  const int b = blockIdx.x;
  const int ln = threadIdx.x;
  for (int i = ln; i < 3600; i += 64) Tl[i / 60][i % 60] = trans[i];
  __syncthreads();

  float gsc = 0.f;
  for (int t = ln; t < T_LEN; t += 64) {
    int tg = tags[t * BATCH + b];
    int pv = (t == 0) ? START_TAG : tags[(t - 1) * BATCH + b];
    gsc += Tl[tg][pv] + feats[(t * BATCH + b) * 64 + tg];
  }
#pragma unroll
  for (int off = 32; off > 0; off >>= 1) gsc += __shfl_down(gsc, off);
  if (ln == 0) gsc += Tl[STOP_TAG][tags[(T_LEN - 1) * BATCH + b]];

  abuf[0][ln] = (ln == START_TAG) ? 0.f : NEGV;
  __syncthreads();
  const float* Trow = Tl[ln < NTAGS ? ln : 0];
  const int myk = (ln < NTAGS) ? ln : 0;
  for (int t = 0; t < T_LEN; ++t) {
    const int cb = t & 1, nb2 = cb ^ 1;
    float m = -1e30f;
    for (int p = 0; p < NTAGS; ++p) m = fmaxf(m, abuf[cb][p] + Trow[p]);
    float ssum = 0.f;
    for (int p = 0; p < NTAGS; ++p) ssum += __expf(abuf[cb][p] + Trow[p] - m);
    float nv = m + __logf(ssum) + feats[(t * BATCH + b) * 64 + myk];
    abuf[nb2][ln] = (ln < NTAGS) ? nv : NEGV;
    __syncthreads();
  }

  float v = (ln < NTAGS) ? (abuf[T_LEN & 1][ln] + Tl[STOP_TAG][ln]) : -1e30f;
  float mm = v;
#pragma unroll
  for (int off = 32; off > 0; off >>= 1) mm = fmaxf(mm, __shfl_down(mm, off));
  mm = __shfl(mm, 0);
  float es = __expf(v - mm);
#pragma unroll
  for (int off = 32; off > 0; off >>= 1) es += __shfl_down(es, off);
  if (ln == 0) out[b] = mm + __logf(es) - gsc;
}

// ---------------------------------------------------------------------------
extern "C" void kernel_launch(void* const* d_in, const int* in_sizes, int n_in,
                              void* d_out, int out_size, void* d_ws, size_t ws_size,
                              hipStream_t stream) {
  (void)in_sizes; (void)n_in; (void)out_size; (void)ws_size;
  const float* sent  = (const float*)d_in[0];
  const int*   tags  = (const int*)d_in[1];
  const float* wih1  = (const float*)d_in[2];
  const float* whh1  = (const float*)d_in[3];
  const float* b1    = (const float*)d_in[4];
  const float* wih   = (const float*)d_in[5];
  const float* whh   = (const float*)d_in[6];
  const float* bias  = (const float*)d_in[7];
  const float* fcw   = (const float*)d_in[8];
  const float* fcb   = (const float*)d_in[9];
  const float* h0    = (const float*)d_in[10];
  const float* c0    = (const float*)d_in[11];
  const float* trans = (const float*)d_in[12];
  float* out = (float*)d_out;

  char* ws = (char*)d_ws;
  size_t off = 0;
  auto alloc = [&](size_t bytes) -> void* {
    void* p = ws + off;
    off = (off + bytes + 255) & ~(size_t)255;
    return p;
  };
  u16* whh_bf = (u16*)alloc((size_t)7 * 2 * 1024 * 256 * 2);
  u16* wih_bf = (u16*)alloc((size_t)6 * 2 * 1024 * 512 * 2);
  u16* fcw_bf = (u16*)alloc((size_t)64 * 512 * 2);
  u16* xw     = (u16*)alloc((size_t)16384 * 2048 * 2);
  u16* ob[3];
  for (int i = 0; i < 3; ++i) ob[i] = (u16*)alloc((size_t)16384 * 512 * 2);
  float* feats = (float*)alloc((size_t)16384 * 64 * 4);
  u16* hG      = (u16*)alloc((size_t)2 * 2 * BATCH * H * 2);  // [parity][dir*128+b][256]
  unsigned* cnt = (unsigned*)alloc((size_t)7 * 8 * 32 * 4);   // per-layer, per-group, padded

  hipMemsetAsync(cnt, 0, (size_t)7 * 8 * 32 * 4, stream);

  hipLaunchKernelGGL(pack_kernel, dim3(4096), dim3(256), 0, stream,
                     whh1, whh, wih, fcw, whh_bf, wih_bf, fcw_bf);
  hipLaunchKernelGGL(xw1_kernel, dim3(131072), dim3(256), 0, stream, sent, wih1, b1, xw);
  hipLaunchKernelGGL(scan_kernel, dim3(32), dim3(256), 0, stream,
                     whh_bf, xw, h0, c0, ob[0], hG, cnt);
  for (int L = 1; L < 7; ++L) {
    const u16* curb = ob[(L - 1) % 3];
    const u16* prevb = (L >= 2) ? ob[(L - 2) % 3] : nullptr;
    hipLaunchKernelGGL(gemm_xw_kernel, dim3(8, 256), dim3(256), 0, stream,
                       curb, prevb, wih_bf + (size_t)(L - 1) * 2 * 1024 * 512,
                       bias + (size_t)(L - 1) * 2048, xw);
    hipLaunchKernelGGL(scan_kernel, dim3(32), dim3(256), 0, stream,
                       whh_bf + (size_t)L * 2 * 1024 * 256, xw,
                       h0 + (size_t)L * 2 * 128 * 256, c0 + (size_t)L * 2 * 128 * 256,
                       ob[L % 3], hG, cnt + (size_t)L * 8 * 32);
  }
  hipLaunchKernelGGL(fc_kernel, dim3(256), dim3(256), 0, stream, ob[0], fcw_bf, fcb, feats);
  hipLaunchKernelGGL(crf_kernel, dim3(128), dim3(64), 0, stream, feats, trans, tags, out);
}

// Round 4
// 5138.409 us; speedup vs baseline: 3.2253x; 1.3007x over previous
//
#include <hip/hip_runtime.h>
#include <stdint.h>

#define T_LEN 128
#define BATCH 128
#define DHID 512
#define H 256
#define NTAGS 60
#define START_TAG 58
#define STOP_TAG 59
#define NEGV -10000.0f

typedef __attribute__((ext_vector_type(8))) short bf16x8;
typedef __attribute__((ext_vector_type(4))) short bf16x4;
typedef __attribute__((ext_vector_type(4))) float floatx4;
typedef unsigned short u16;
typedef unsigned long long u64c;

__device__ __forceinline__ u16 f2bf(float f) {
  union { float f; uint32_t u; } c; c.f = f;
  uint32_t u = c.u;
  u += 0x7FFFu + ((u >> 16) & 1u);
  return (u16)(u >> 16);
}
__device__ __forceinline__ float bf2f(u16 h) {
  union { uint32_t u; float f; } c; c.u = ((uint32_t)h) << 16;
  return c.f;
}
__device__ __forceinline__ float sigmf(float x) { return 1.0f / (1.0f + __expf(-x)); }
__device__ __forceinline__ float tanhfast(float x) {
  x = fminf(fmaxf(x, -15.0f), 15.0f);
  float e = __expf(2.0f * x);
  return (e - 1.0f) / (e + 1.0f);
}

// ---------------------------------------------------------------------------
// Pack fp32 weights -> bf16 workspace copies.
// ---------------------------------------------------------------------------
__global__ void pack_kernel(const float* __restrict__ whh1, const float* __restrict__ whh,
                            const float* __restrict__ wih, const float* __restrict__ fcw,
                            u16* __restrict__ whh_bf, u16* __restrict__ wih_bf,
                            u16* __restrict__ fcw_bf) {
  const int n_whh1 = 2 * 1024 * 256;
  const int n_whh  = 6 * 2 * 1024 * 256;
  const int n_wih  = 6 * 2 * 1024 * 512;
  const int n_fcw  = 64 * 512;
  const int total = n_whh1 + n_whh + n_wih + n_fcw;
  for (int i = blockIdx.x * blockDim.x + threadIdx.x; i < total; i += gridDim.x * blockDim.x) {
    if (i < n_whh1) {
      whh_bf[i] = f2bf(whh1[i]);
    } else if (i < n_whh1 + n_whh) {
      whh_bf[i] = f2bf(whh[i - n_whh1]);
    } else if (i < n_whh1 + n_whh + n_wih) {
      int j = i - n_whh1 - n_whh;
      wih_bf[j] = f2bf(wih[j]);
    } else {
      int j = i - n_whh1 - n_whh - n_wih;
      int row = j >> 9;
      fcw_bf[j] = (row < NTAGS) ? f2bf(fcw[j]) : (u16)0;
    }
  }
}

// ---------------------------------------------------------------------------
// Layer-1 xw, TRANSPOSED layout: xw[t][col(2048)][b(128)].
// ---------------------------------------------------------------------------
__global__ void xw1_kernel(const float* __restrict__ sent, const float* __restrict__ wih1,
                           const float* __restrict__ b1, u16* __restrict__ xw) {
  int idx = blockIdx.x * blockDim.x + threadIdx.x;
  int b = idx & 127;
  int rest = idx >> 7;
  int col = rest & 2047;
  int t = rest >> 11;
  int row = t * BATCH + b;
  const float* x = sent + row * 3;
  const float* w = wih1 + col * 3;
  float a = b1[col] + x[0] * w[0] + x[1] * w[1] + x[2] * w[2];
  xw[idx] = f2bf(a);
}

// ---------------------------------------------------------------------------
// xw GEMM layers 2..7: out transposed xw[t][col][b].
// ---------------------------------------------------------------------------
__launch_bounds__(256, 4)
__global__ void gemm_xw_kernel(const u16* __restrict__ cur, const u16* __restrict__ prev,
                               const u16* __restrict__ W, const float* __restrict__ bias,
                               u16* __restrict__ xw) {
  __shared__ __align__(16) u16 As[64][72];
  const int nbase = blockIdx.x * 256;
  const int m0 = blockIdx.y * 64;
  const int tid = threadIdx.x;
  const int wv = tid >> 6, ln = tid & 63;
  const int c16 = ln & 15, q = ln >> 4;
  const int ncol0 = nbase + wv * 64;

  floatx4 acc[4][4];
#pragma unroll
  for (int i = 0; i < 4; ++i)
#pragma unroll
    for (int j = 0; j < 4; ++j) { acc[i][j][0] = 0.f; acc[i][j][1] = 0.f; acc[i][j][2] = 0.f; acc[i][j][3] = 0.f; }

  for (int kc = 0; kc < 8; ++kc) {
    {
      int u = tid * 2;
#pragma unroll
      for (int z = 0; z < 2; ++z, ++u) {
        int r = u >> 3, cu = (u & 7) * 8;
        int gaddr = (m0 + r) * DHID + kc * 64 + cu;
        bf16x8 a8 = *(const bf16x8*)(cur + gaddr);
        u16* ap = (u16*)&a8;
        if (prev) {
          bf16x8 p8 = *(const bf16x8*)(prev + gaddr);
          u16* pp = (u16*)&p8;
#pragma unroll
          for (int e = 0; e < 8; ++e) {
            float va = (ap[e] & 0x8000) ? 0.f : bf2f(ap[e]);
            float vp = (pp[e] & 0x8000) ? 0.f : bf2f(pp[e]);
            ap[e] = f2bf(va + vp);
          }
        } else {
#pragma unroll
          for (int e = 0; e < 8; ++e) if (ap[e] & 0x8000) ap[e] = 0;
        }
        *(bf16x8*)(&As[r][cu]) = a8;
      }
    }
    __syncthreads();
#pragma unroll
    for (int kt = 0; kt < 2; ++kt) {
      int kg = kc * 64 + kt * 32 + q * 8;
      bf16x8 bfr[4];
#pragma unroll
      for (int nt = 0; nt < 4; ++nt)
        bfr[nt] = *(const bf16x8*)(W + (ncol0 + nt * 16 + c16) * DHID + kg);
      bf16x8 afr[4];
#pragma unroll
      for (int mt = 0; mt < 4; ++mt)
        afr[mt] = *(const bf16x8*)(&As[mt * 16 + c16][kt * 32 + q * 8]);
#pragma unroll
      for (int nt = 0; nt < 4; ++nt)
#pragma unroll
        for (int mt = 0; mt < 4; ++mt)
          acc[nt][mt] = __builtin_amdgcn_mfma_f32_16x16x32_bf16(afr[mt], bfr[nt], acc[nt][mt], 0, 0, 0);
    }
    __syncthreads();
  }
  const int t = m0 >> 7;
  const int bb = (m0 & 127) + q * 4;
#pragma unroll
  for (int nt = 0; nt < 4; ++nt) {
    int col = ncol0 + nt * 16 + c16;
    float bv = bias[col];
#pragma unroll
    for (int mt = 0; mt < 4; ++mt) {
      bf16x4 v;
#pragma unroll
      for (int r = 0; r < 4; ++r) v[r] = (short)f2bf(acc[nt][mt][r] + bv);
      *(bf16x4*)(xw + ((size_t)t * 2048 + col) * 128 + bb + mt * 16) = v;
    }
  }
}

// ---------------------------------------------------------------------------
// LSTM scan, hidden-split design. Grid: 32 blocks of 256 threads (4 waves).
//   blockIdx.x = dir*16 + bc*4 + dq
// Block keeps its W_hh slice (4g x 64 cols x 256) in LDS (stride 268: 2-way
// bank pattern on b128 frag reads = free). Per step:
//   xw prefetch -> wave0 polls group flag -> cooperative h-tile load from LLC
//   into LDS hin (ONE copy, 8-B sc1 loads, coalesced) -> ds_read frags + MFMA
//   -> gates -> hstage -> 16-B publish to hG[pn] (sc1) + obuf -> barrier
//   (drains stores) -> tid0 bumps group counter.
// ---------------------------------------------------------------------------
__launch_bounds__(256, 1)
__global__ void scan_kernel(const u16* __restrict__ whh, const u16* __restrict__ xw,
                            const float* __restrict__ h0, const float* __restrict__ c0,
                            u16* __restrict__ obuf, u16* __restrict__ hG,
                            unsigned* __restrict__ cnt) {
  __shared__ __align__(16) u16 Wl[256][268];   // 137216 B
  __shared__ __align__(16) u16 hin[32][268];   //  17152 B
  __shared__ __align__(16) u16 hstage[32][68]; //   4352 B  (total 158720 <= 160K)
  const int dq  = blockIdx.x & 3;
  const int bc  = (blockIdx.x >> 2) & 3;
  const int dir = blockIdx.x >> 4;
  const int b0  = bc * 32;
  const int tid = threadIdx.x;
  const int wv = tid >> 6, ln = tid & 63;
  const int c16 = ln & 15, q = ln >> 4;
  const int colb = dq * 64 + wv * 16;
  unsigned* grpcnt = cnt + (dir * 4 + bc) * 32;

  // --- one-time: W slice -> LDS ---
  {
    int g = tid >> 6, lc = tid & 63;
    const u16* wrow = whh + ((size_t)dir * 1024 + g * 256 + dq * 64 + lc) * H;
    for (int kk = 0; kk < 256; kk += 8)
      *(bf16x8*)(&Wl[g * 64 + lc][kk]) = *(const bf16x8*)(wrow + kk);
  }
  // --- one-time: publish h0 slice into hG[0] (agent stores) ---
  {
    int bl = tid >> 3, cr = (tid & 7) * 8;
    const float* hrow = h0 + ((size_t)dir * BATCH + b0 + bl) * H + dq * 64 + cr;
    u16 tmp[8];
#pragma unroll
    for (int j = 0; j < 8; ++j) tmp[j] = f2bf(hrow[j]);
    u64c* src = (u64c*)tmp;
    u64c* dst = (u64c*)(hG + ((size_t)dir * BATCH + b0 + bl) * H + dq * 64 + cr);
    __hip_atomic_store(&dst[0], src[0], __ATOMIC_RELAXED, __HIP_MEMORY_SCOPE_AGENT);
    __hip_atomic_store(&dst[1], src[1], __ATOMIC_RELAXED, __HIP_MEMORY_SCOPE_AGENT);
  }
  // --- c init (fp32, registers) ---
  float creg[2][4];
#pragma unroll
  for (int mt = 0; mt < 2; ++mt)
#pragma unroll
    for (int r = 0; r < 4; ++r)
      creg[mt][r] = c0[((size_t)dir * BATCH + b0 + mt * 16 + q * 4 + r) * H + colb + c16];

  __syncthreads();  // drains h0 publish (barrier implies vmcnt(0))
  if (tid == 0) __hip_atomic_fetch_add(grpcnt, 1u, __ATOMIC_RELAXED, __HIP_MEMORY_SCOPE_AGENT);

  const size_t hGhalf = (size_t)2 * BATCH * H;
  const int crow = tid >> 3;   // coop-load row 0..31
  const int cchunk = tid & 7;  // coop-load col chunk (32 elems each)

  for (int s = 0; s < T_LEN; ++s) {
    const int t = dir ? (T_LEN - 1 - s) : s;
    const int p = s & 1, pn = p ^ 1;

    // 1) xw prefetch (independent of peers; completes during flag wait)
    bf16x4 xwv[4][2];
#pragma unroll
    for (int g = 0; g < 4; ++g)
#pragma unroll
      for (int mt = 0; mt < 2; ++mt)
        xwv[g][mt] = *(const bf16x4*)(xw + ((size_t)t * 2048 + dir * 1024 + g * 256 + colb + c16) * 128 +
                                      b0 + mt * 16 + q * 4);

    // 2) wave 0 polls the group flag; others wait at the barrier
    if (wv == 0) {
      const unsigned target = 4u * (unsigned)(s + 1);
      while (__hip_atomic_load(grpcnt, __ATOMIC_RELAXED, __HIP_MEMORY_SCOPE_AGENT) < target)
        __builtin_amdgcn_s_sleep(2);
    }
    __syncthreads();

    // 3) cooperative h-tile load from LLC -> LDS hin (one copy per block)
    {
      const u64c* src = (const u64c*)(hG + p * hGhalf + ((size_t)dir * BATCH + b0 + crow) * H + cchunk * 32);
      u64c vv[8];
#pragma unroll
      for (int j = 0; j < 8; ++j)
        vv[j] = __hip_atomic_load(&src[j], __ATOMIC_RELAXED, __HIP_MEMORY_SCOPE_AGENT);
#pragma unroll
      for (int k = 0; k < 4; ++k) {
        union { u64c v[2]; bf16x8 f; } u;
        u.v[0] = vv[2 * k]; u.v[1] = vv[2 * k + 1];
        *(bf16x8*)(&hin[crow][cchunk * 32 + k * 8]) = u.f;
      }
    }
    __syncthreads();

    // 4) A-frags from LDS hin
    bf16x8 afrag[2][8];
#pragma unroll
    for (int mt = 0; mt < 2; ++mt)
#pragma unroll
      for (int kt = 0; kt < 8; ++kt)
        afrag[mt][kt] = *(const bf16x8*)(&hin[mt * 16 + c16][kt * 32 + q * 8]);

    // 5) MFMA: acc init from xw, B-frags from LDS W
    floatx4 acc[4][2];
#pragma unroll
    for (int g = 0; g < 4; ++g)
#pragma unroll
      for (int mt = 0; mt < 2; ++mt)
#pragma unroll
        for (int r = 0; r < 4; ++r)
          acc[g][mt][r] = bf2f((u16)xwv[g][mt][r]);
#pragma unroll
    for (int g = 0; g < 4; ++g) {
      bf16x8 bfr[8];
#pragma unroll
      for (int kt = 0; kt < 8; ++kt)
        bfr[kt] = *(const bf16x8*)(&Wl[g * 64 + wv * 16 + c16][kt * 32 + q * 8]);
#pragma unroll
      for (int kt = 0; kt < 8; ++kt)
#pragma unroll
        for (int mt = 0; mt < 2; ++mt)
          acc[g][mt] = __builtin_amdgcn_mfma_f32_16x16x32_bf16(afrag[mt][kt], bfr[kt], acc[g][mt], 0, 0, 0);
    }

    // 6) gates -> h' into hstage (LDS)
#pragma unroll
    for (int mt = 0; mt < 2; ++mt)
#pragma unroll
      for (int r = 0; r < 4; ++r) {
        float ig = sigmf(acc[0][mt][r]);
        float fg = sigmf(acc[1][mt][r]);
        float gg = tanhfast(acc[2][mt][r]);
        float og = sigmf(acc[3][mt][r]);
        float cn = fg * creg[mt][r] + ig * gg;
        creg[mt][r] = cn;
        hstage[mt * 16 + q * 4 + r][wv * 16 + c16] = f2bf(og * tanhfast(cn));
      }
    __syncthreads();

    // 7) publish h' (16-B chunks: 2 sc1 u64 stores) + obuf write
    {
      int bl = tid >> 3, cr = (tid & 7) * 8;
      bf16x8 hv = *(const bf16x8*)(&hstage[bl][cr]);
      u64c* src = (u64c*)&hv;
      u64c* dst = (u64c*)(hG + pn * hGhalf + ((size_t)dir * BATCH + b0 + bl) * H + dq * 64 + cr);
      __hip_atomic_store(&dst[0], src[0], __ATOMIC_RELAXED, __HIP_MEMORY_SCOPE_AGENT);
      __hip_atomic_store(&dst[1], src[1], __ATOMIC_RELAXED, __HIP_MEMORY_SCOPE_AGENT);
      *(bf16x8*)(obuf + ((size_t)t * BATCH + b0 + bl) * DHID + dir * H + dq * 64 + cr) = hv;
    }
    __syncthreads();  // drains publishes (vmcnt(0)) before flag bump
    if (tid == 0) __hip_atomic_fetch_add(grpcnt, 1u, __ATOMIC_RELAXED, __HIP_MEMORY_SCOPE_AGENT);
  }
}

// ---------------------------------------------------------------------------
// FC: feats[16384][64] = out7[16384][512] @ fcw^T + fc_b
// ---------------------------------------------------------------------------
__launch_bounds__(256, 4)
__global__ void fc_kernel(const u16* __restrict__ A, const u16* __restrict__ W,
                          const float* __restrict__ fb, float* __restrict__ feats) {
  const int tid = threadIdx.x, wv = tid >> 6, ln = tid & 63;
  const int c16 = ln & 15, q = ln >> 4;
  const int m0 = blockIdx.x * 64 + wv * 16;
  floatx4 acc[4];
#pragma unroll
  for (int i = 0; i < 4; ++i) { acc[i][0] = 0.f; acc[i][1] = 0.f; acc[i][2] = 0.f; acc[i][3] = 0.f; }
#pragma unroll
  for (int kt = 0; kt < 16; ++kt) {
    bf16x8 a = *(const bf16x8*)(A + (m0 + c16) * DHID + kt * 32 + q * 8);
#pragma unroll
    for (int nt = 0; nt < 4; ++nt) {
      bf16x8 b = *(const bf16x8*)(W + (nt * 16 + c16) * DHID + kt * 32 + q * 8);
      acc[nt] = __builtin_amdgcn_mfma_f32_16x16x32_bf16(a, b, acc[nt], 0, 0, 0);
    }
  }
#pragma unroll
  for (int nt = 0; nt < 4; ++nt) {
    int n = nt * 16 + c16;
    if (n < NTAGS) {
      float bv = fb[n];
#pragma unroll
      for (int r = 0; r < 4; ++r)
        feats[(m0 + q * 4 + r) * 64 + n] = acc[nt][r] + bv;
    }
  }
}

// ---------------------------------------------------------------------------
// CRF: one wave per batch item.
// ---------------------------------------------------------------------------
__launch_bounds__(64, 1)
__global__ void crf_kernel(const float* __restrict__ feats, const float* __restrict__ trans,
                           const int* __restrict__ tags, float* __restrict__ out) {
  __shared__ float Tl[60][65];
  __shared__ float abuf[2][64];
  const int b = blockIdx.x;
  const int ln = threadIdx.x;
  for (int i = ln; i < 3600; i += 64) Tl[i / 60][i % 60] = trans[i];
  __syncthreads();

  float gsc = 0.f;
  for (int t = ln; t < T_LEN; t += 64) {
    int tg = tags[t * BATCH + b];
    int pv = (t == 0) ? START_TAG : tags[(t - 1) * BATCH + b];
    gsc += Tl[tg][pv] + feats[(t * BATCH + b) * 64 + tg];
  }
#pragma unroll
  for (int off = 32; off > 0; off >>= 1) gsc += __shfl_down(gsc, off);
  if (ln == 0) gsc += Tl[STOP_TAG][tags[(T_LEN - 1) * BATCH + b]];

  abuf[0][ln] = (ln == START_TAG) ? 0.f : NEGV;
  __syncthreads();
  const float* Trow = Tl[ln < NTAGS ? ln : 0];
  const int myk = (ln < NTAGS) ? ln : 0;
  for (int t = 0; t < T_LEN; ++t) {
    const int cb = t & 1, nb2 = cb ^ 1;
    float m = -1e30f;
    for (int p = 0; p < NTAGS; ++p) m = fmaxf(m, abuf[cb][p] + Trow[p]);
    float ssum = 0.f;
    for (int p = 0; p < NTAGS; ++p) ssum += __expf(abuf[cb][p] + Trow[p] - m);
    float nv = m + __logf(ssum) + feats[(t * BATCH + b) * 64 + myk];
    abuf[nb2][ln] = (ln < NTAGS) ? nv : NEGV;
    __syncthreads();
  }

  float v = (ln < NTAGS) ? (abuf[T_LEN & 1][ln] + Tl[STOP_TAG][ln]) : -1e30f;
  float mm = v;
#pragma unroll
  for (int off = 32; off > 0; off >>= 1) mm = fmaxf(mm, __shfl_down(mm, off));
  mm = __shfl(mm, 0);
  float es = __expf(v - mm);
#pragma unroll
  for (int off = 32; off > 0; off >>= 1) es += __shfl_down(es, off);
  if (ln == 0) out[b] = mm + __logf(es) - gsc;
}

// ---------------------------------------------------------------------------
extern "C" void kernel_launch(void* const* d_in, const int* in_sizes, int n_in,
                              void* d_out, int out_size, void* d_ws, size_t ws_size,
                              hipStream_t stream) {
  (void)in_sizes; (void)n_in; (void)out_size; (void)ws_size;
  const float* sent  = (const float*)d_in[0];
  const int*   tags  = (const int*)d_in[1];
  const float* wih1  = (const float*)d_in[2];
  const float* whh1  = (const float*)d_in[3];
  const float* b1    = (const float*)d_in[4];
  const float* wih   = (const float*)d_in[5];
  const float* whh   = (const float*)d_in[6];
  const float* bias  = (const float*)d_in[7];
  const float* fcw   = (const float*)d_in[8];
  const float* fcb   = (const float*)d_in[9];
  const float* h0    = (const float*)d_in[10];
  const float* c0    = (const float*)d_in[11];
  const float* trans = (const float*)d_in[12];
  float* out = (float*)d_out;

  char* ws = (char*)d_ws;
  size_t off = 0;
  auto alloc = [&](size_t bytes) -> void* {
    void* p = ws + off;
    off = (off + bytes + 255) & ~(size_t)255;
    return p;
  };
  u16* whh_bf = (u16*)alloc((size_t)7 * 2 * 1024 * 256 * 2);
  u16* wih_bf = (u16*)alloc((size_t)6 * 2 * 1024 * 512 * 2);
  u16* fcw_bf = (u16*)alloc((size_t)64 * 512 * 2);
  u16* xw     = (u16*)alloc((size_t)16384 * 2048 * 2);
  u16* ob[3];
  for (int i = 0; i < 3; ++i) ob[i] = (u16*)alloc((size_t)16384 * 512 * 2);
  float* feats = (float*)alloc((size_t)16384 * 64 * 4);
  u16* hG      = (u16*)alloc((size_t)2 * 2 * BATCH * H * 2);
  unsigned* cnt = (unsigned*)alloc((size_t)7 * 8 * 32 * 4);

  hipMemsetAsync(cnt, 0, (size_t)7 * 8 * 32 * 4, stream);

  hipLaunchKernelGGL(pack_kernel, dim3(4096), dim3(256), 0, stream,
                     whh1, whh, wih, fcw, whh_bf, wih_bf, fcw_bf);
  hipLaunchKernelGGL(xw1_kernel, dim3(131072), dim3(256), 0, stream, sent, wih1, b1, xw);
  hipLaunchKernelGGL(scan_kernel, dim3(32), dim3(256), 0, stream,
                     whh_bf, xw, h0, c0, ob[0], hG, cnt);
  for (int L = 1; L < 7; ++L) {
    const u16* curb = ob[(L - 1) % 3];
    const u16* prevb = (L >= 2) ? ob[(L - 2) % 3] : nullptr;
    hipLaunchKernelGGL(gemm_xw_kernel, dim3(8, 256), dim3(256), 0, stream,
                       curb, prevb, wih_bf + (size_t)(L - 1) * 2 * 1024 * 512,
                       bias + (size_t)(L - 1) * 2048, xw);
    hipLaunchKernelGGL(scan_kernel, dim3(32), dim3(256), 0, stream,
                       whh_bf + (size_t)L * 2 * 1024 * 256, xw,
                       h0 + (size_t)L * 2 * 128 * 256, c0 + (size_t)L * 2 * 128 * 256,
                       ob[L % 3], hG, cnt + (size_t)L * 8 * 32);
  }
  hipLaunchKernelGGL(fc_kernel, dim3(256), dim3(256), 0, stream, ob[0], fcw_bf, fcb, feats);
  hipLaunchKernelGGL(crf_kernel, dim3(128), dim3(64), 0, stream, feats, trans, tags, out);
}